// Round 1
// baseline (1167.463 us; speedup 1.0000x reference)
//
#include <hip/hip_runtime.h>
#include <math.h>
#include <cstddef>

#define B_ 16
#define T_ 256
#define D_ 128
#define H_ 128
#define L_ 4
#define G_ 512          // 4*H
#define NC_ 10
#define EPS_ 1e-5f

// ---------------- device helpers ----------------
__device__ __forceinline__ float sigmoid_(float x) {
    x = fminf(fmaxf(x, -30.f), 30.f);
    return 1.f / (1.f + __expf(-x));
}
__device__ __forceinline__ float tanh_(float x) {
    float ax = fminf(fabsf(x), 15.f);     // tanh(15) == 1.0f in fp32; avoids exp overflow
    float e = __expf(2.f * ax);
    float t = 1.f - 2.f / (e + 1.f);
    return copysignf(t, x);
}

// ---------------- stage 1: input normalize ----------------
// per-(b,d) sum & sumsq over T
__global__ __launch_bounds__(512) void stats_bd(const float* __restrict__ x,
                                                float* __restrict__ sum_bd,
                                                float* __restrict__ sq_bd) {
    int b = blockIdx.x;
    int tid = threadIdx.x;
    int d = tid & 127, r = tid >> 7;      // 128 features x 4 t-strips
    const float* xb = x + (size_t)b * T_ * D_;
    float s = 0.f, q = 0.f;
    for (int t = r; t < T_; t += 4) {
        float v = xb[t * D_ + d];
        s += v; q += v * v;
    }
    __shared__ float ls[512], lq[512];
    ls[tid] = s; lq[tid] = q;
    __syncthreads();
    if (r == 0) {
        s = ls[d] + ls[d + 128] + ls[d + 256] + ls[d + 384];
        q = lq[d] + lq[d + 128] + lq[d + 256] + lq[d + 384];
        sum_bd[b * 128 + d] = s;
        sq_bd[b * 128 + d] = q;
    }
}

// per-d global std (unbiased, ddof=1) + EPS   (means/std are detached constants)
__global__ __launch_bounds__(128) void stats_d(const float* __restrict__ sum_bd,
                                               const float* __restrict__ sq_bd,
                                               float* __restrict__ sdv) {
    int d = threadIdx.x;
    float s = 0.f, q = 0.f;
    for (int b = 0; b < B_; b++) { s += sum_bd[b * 128 + d]; q += sq_bd[b * 128 + d]; }
    float n = (float)(B_ * T_);
    float m = s / n;
    float varu = (q - n * m * m) / (n - 1.f);
    varu = fmaxf(varu, 0.f);
    sdv[d] = sqrtf(varu) + EPS_;
}

// fused: x1=(x-m_d)/s_d then InstanceNorm over T  ==  (x-mu_bd)/sqrt(varT_bd + eps*s_d^2)
__global__ __launch_bounds__(256) void normalize_x(const float* __restrict__ x,
                                                   const float* __restrict__ sum_bd,
                                                   const float* __restrict__ sq_bd,
                                                   const float* __restrict__ sdv,
                                                   float* __restrict__ xn) {
    int idx = blockIdx.x * 256 + threadIdx.x;   // B*T*D = 524288
    int d = idx & 127;
    int b = idx >> 15;                          // T*D = 32768
    int bd = b * 128 + d;
    float mu = sum_bd[bd] * (1.f / T_);
    float varT = sq_bd[bd] * (1.f / T_) - mu * mu;
    float s = sdv[d];
    float inv = rsqrtf(fmaxf(varT, 0.f) + EPS_ * s * s);
    xn[idx] = (x[idx] - mu) * inv;
}

// ---------------- generic K=128 GEMM: C[M,N] = A[M,128] * Bw[N,128]^T + b1 (+ b2) ----------------
__global__ __launch_bounds__(256) void gemm_bias_k128(const float* __restrict__ A,
                                                      const float* __restrict__ Bw,
                                                      const float* __restrict__ b1,
                                                      const float* __restrict__ b2,
                                                      float* __restrict__ C, int N) {
    __shared__ __align__(16) float As[16][64];
    __shared__ __align__(16) float Bs[16][64];
    int tid = threadIdx.x;
    int m0 = blockIdx.x * 64, n0 = blockIdx.y * 64;
    int lr = tid >> 2;            // 0..63 tile row for staging
    int lc = (tid & 3) << 2;      // k offset {0,4,8,12}
    int tm = (tid >> 4) << 2;     // micro-tile row base
    int tn = (tid & 15) << 2;     // micro-tile col base
    float acc[4][4] = {};
    const float* Arow = A + (size_t)(m0 + lr) * 128 + lc;
    const float* Brow = Bw + (size_t)(n0 + lr) * 128 + lc;
    for (int kb = 0; kb < 128; kb += 16) {
        float4 av = *(const float4*)(Arow + kb);
        float4 bv = *(const float4*)(Brow + kb);
        __syncthreads();
        As[lc + 0][lr] = av.x; As[lc + 1][lr] = av.y; As[lc + 2][lr] = av.z; As[lc + 3][lr] = av.w;
        Bs[lc + 0][lr] = bv.x; Bs[lc + 1][lr] = bv.y; Bs[lc + 2][lr] = bv.z; Bs[lc + 3][lr] = bv.w;
        __syncthreads();
#pragma unroll
        for (int k = 0; k < 16; k++) {
            float4 a4 = *(const float4*)&As[k][tm];
            float4 b4 = *(const float4*)&Bs[k][tn];
            float ar[4] = {a4.x, a4.y, a4.z, a4.w};
            float br[4] = {b4.x, b4.y, b4.z, b4.w};
#pragma unroll
            for (int i = 0; i < 4; i++)
#pragma unroll
                for (int j = 0; j < 4; j++)
                    acc[i][j] = fmaf(ar[i], br[j], acc[i][j]);
        }
    }
#pragma unroll
    for (int i = 0; i < 4; i++) {
        int row = m0 + tm + i;
#pragma unroll
        for (int j = 0; j < 4; j++) {
            int col = n0 + tn + j;
            float bias = b1[col] + (b2 ? b2[col] : 0.f);
            C[(size_t)row * N + col] = acc[i][j] + bias;
        }
    }
}

// ---------------- recurrent LSTM scan (one workgroup per batch) ----------------
__global__ __launch_bounds__(512, 2) void lstm_scan(const float* __restrict__ gbuf,
                                                    const float* __restrict__ Whh,
                                                    float* __restrict__ hout) {
    int b = blockIdx.x;
    int g = threadIdx.x;                      // gate row 0..511 (i,f,g,o blocks of 128)
    __shared__ __align__(16) float hsh[128];
    __shared__ float gact[512];
    float4 w4[32];                            // Whh row g in registers (128 VGPRs)
    const float4* wr = (const float4*)(Whh + (size_t)g * 128);
#pragma unroll
    for (int j = 0; j < 32; j++) w4[j] = wr[j];
    float c = 0.f;
    if (g < 128) hsh[g] = 0.f;
    const float* gb = gbuf + (size_t)b * T_ * G_;
    float* hob = hout + (size_t)b * T_ * H_;
    float pre = gb[g];                        // t = 0 preactivation (x-proj + biases)
    __syncthreads();
    for (int t = 0; t < T_; t++) {
        float pre_nxt = (t + 1 < T_) ? gb[(size_t)(t + 1) * G_ + g] : 0.f;  // prefetch
        float d0 = 0.f, d1 = 0.f, d2 = 0.f, d3 = 0.f;
        const float4* h4 = (const float4*)hsh;
#pragma unroll
        for (int j = 0; j < 32; j++) {
            float4 hv = h4[j];                // same-address broadcast, conflict-free
            d0 = fmaf(w4[j].x, hv.x, d0);
            d1 = fmaf(w4[j].y, hv.y, d1);
            d2 = fmaf(w4[j].z, hv.z, d2);
            d3 = fmaf(w4[j].w, hv.w, d3);
        }
        float z = pre + ((d0 + d1) + (d2 + d3));
        float a = ((g >> 7) == 2) ? tanh_(z) : sigmoid_(z);
        gact[g] = a;
        __syncthreads();
        if (g < 128) {
            float ai = gact[g], af = gact[128 + g], ag = gact[256 + g], ao = gact[384 + g];
            c = fmaf(af, c, ai * ag);
            float hn = ao * tanh_(c);
            hsh[g] = hn;
            hob[(size_t)t * H_ + g] = hn;
        }
        pre = pre_nxt;
        __syncthreads();
    }
}

// ---------------- InstanceNorm stats (per (b,ch) over T) ----------------
__global__ __launch_bounds__(512) void in_stats(const float* __restrict__ in,
                                                float* __restrict__ mu,
                                                float* __restrict__ inv) {
    int b = blockIdx.x;
    int tid = threadIdx.x;
    int h = tid & 127, r = tid >> 7;
    const float* ib = in + (size_t)b * T_ * H_;
    float s = 0.f, q = 0.f;
    for (int t = r; t < T_; t += 4) { float v = ib[t * H_ + h]; s += v; q += v * v; }
    __shared__ float ls[512], lq[512];
    ls[tid] = s; lq[tid] = q;
    __syncthreads();
    if (r == 0) {
        s = ls[h] + ls[h + 128] + ls[h + 256] + ls[h + 384];
        q = lq[h] + lq[h + 128] + lq[h + 256] + lq[h + 384];
        float m = s * (1.f / T_);
        float v = q * (1.f / T_) - m * m;
        mu[b * 128 + h] = m;
        inv[b * 128 + h] = rsqrtf(fmaxf(v, 0.f) + EPS_);
    }
}

__global__ __launch_bounds__(256) void apply_in(const float* __restrict__ in,
                                                const float* __restrict__ mu,
                                                const float* __restrict__ inv,
                                                float* __restrict__ out) {
    int idx = blockIdx.x * 256 + threadIdx.x;
    int h = idx & 127;
    int b = idx >> 15;
    out[idx] = (in[idx] - mu[b * 128 + h]) * inv[b * 128 + h];
}

// ---------------- attention score l[b,t] = sum_h tanh(ph + IN(px)) * attn_w ----------------
__global__ __launch_bounds__(128) void score_kernel(const float* __restrict__ ph,
                                                    const float* __restrict__ px,
                                                    const float* __restrict__ mu_px,
                                                    const float* __restrict__ inv_px,
                                                    const float* __restrict__ attn_w,
                                                    float* __restrict__ lsc) {
    int bt = blockIdx.x;
    int b = bt >> 8;
    int h = threadIdx.x;
    size_t o = (size_t)bt * 128 + h;
    float v = ph[o] + (px[o] - mu_px[b * 128 + h]) * inv_px[b * 128 + h];
    float sv = tanh_(v) * attn_w[h];
    __shared__ float red[128];
    red[h] = sv;
    __syncthreads();
    for (int off = 64; off > 0; off >>= 1) {
        if (h < off) red[h] += red[h + off];
        __syncthreads();
    }
    if (h == 0) lsc[bt] = red[0];
}

// softmax over t; attention_map[b,t,d] = softmax_t(l)[t] / D  (logits constant across d)
__global__ __launch_bounds__(256) void softmax_att(const float* __restrict__ lsc,
                                                   float* __restrict__ wsm,
                                                   float* __restrict__ out_att) {
    int b = blockIdx.x;
    int t = threadIdx.x;
    float v = lsc[b * 256 + t];
    __shared__ float red[256];
    red[t] = v; __syncthreads();
    for (int off = 128; off > 0; off >>= 1) { if (t < off) red[t] = fmaxf(red[t], red[t + off]); __syncthreads(); }
    float mx = red[0]; __syncthreads();
    float e = __expf(v - mx);
    red[t] = e; __syncthreads();
    for (int off = 128; off > 0; off >>= 1) { if (t < off) red[t] += red[t + off]; __syncthreads(); }
    float s = red[0];
    float w = e / s;
    wsm[b * 256 + t] = w;
    __shared__ float wl[256];
    wl[t] = w; __syncthreads();
    float* ob = out_att + (size_t)b * T_ * D_;
    const float invD = 1.f / (float)D_;
    for (int i = t; i < T_ * D_; i += 256) ob[i] = wl[i >> 7] * invD;
}

// context[b,h] = sum_t ph * w;  out = context @ fc_w^T + fc_b
__global__ __launch_bounds__(128) void final_kernel(const float* __restrict__ ph,
                                                    const float* __restrict__ wsm,
                                                    const float* __restrict__ fc_w,
                                                    const float* __restrict__ fc_b,
                                                    float* __restrict__ out) {
    int b = blockIdx.x;
    int h = threadIdx.x;
    const float* pb = ph + (size_t)b * T_ * H_;
    const float* wb = wsm + b * 256;
    float acc = 0.f;
    for (int t = 0; t < T_; t++) acc = fmaf(pb[t * H_ + h], wb[t], acc);
    __shared__ float ctx[128];
    ctx[h] = acc;
    __syncthreads();
    if (h < NC_) {
        float s = fc_b[h];
        const float* fw = fc_w + h * 128;
        for (int k = 0; k < 128; k++) s = fmaf(ctx[k], fw[k], s);
        out[b * NC_ + h] = s;
    }
}

// ---------------- launcher ----------------
extern "C" void kernel_launch(void* const* d_in, const int* in_sizes, int n_in,
                              void* d_out, int out_size, void* d_ws, size_t ws_size,
                              hipStream_t stream) {
    const float* x        = (const float*)d_in[0];
    const float* Wih      = (const float*)d_in[1];
    const float* Whh      = (const float*)d_in[2];
    const float* bih      = (const float*)d_in[3];
    const float* bhh      = (const float*)d_in[4];
    const float* proj_h_w = (const float*)d_in[5];
    const float* proj_h_b = (const float*)d_in[6];
    const float* proj_x_w = (const float*)d_in[7];
    const float* proj_x_b = (const float*)d_in[8];
    const float* attn_w   = (const float*)d_in[9];
    const float* fc_w     = (const float*)d_in[10];
    const float* fc_b     = (const float*)d_in[11];
    float* out = (float*)d_out;

    float* ws = (float*)d_ws;
    const size_t NTD = (size_t)B_ * T_ * D_;   // 524288
    float* xnorm = ws;
    float* hbufA = xnorm + NTD;
    float* hbufB = hbufA + NTD;
    float* gbuf  = hbufB + NTD;                // 2097152 floats
    float* lnorm = gbuf;                       // reuse gbuf region after scans
    float* ph    = gbuf + NTD;
    float* px    = gbuf + 2 * NTD;
    float* sum_bd = gbuf + 4 * NTD;
    float* sq_bd  = sum_bd + 2048;
    float* sdv    = sq_bd + 2048;
    float* mu_ln  = sdv + 128;
    float* inv_ln = mu_ln + 2048;
    float* mu_px  = inv_ln + 2048;
    float* inv_px = mu_px + 2048;
    float* lsc    = inv_px + 2048;
    float* wsm    = lsc + 4096;

    // input normalize (global detached norm + instancenorm, fused)
    stats_bd<<<16, 512, 0, stream>>>(x, sum_bd, sq_bd);
    stats_d<<<1, 128, 0, stream>>>(sum_bd, sq_bd, sdv);
    normalize_x<<<2048, 256, 0, stream>>>(x, sum_bd, sq_bd, sdv, xnorm);

    // LSTM stack
    const float* lin = xnorm;
    float* louts[4] = {hbufA, hbufB, hbufA, hbufB};
    for (int l = 0; l < L_; l++) {
        dim3 g1(64, 8);
        gemm_bias_k128<<<g1, 256, 0, stream>>>(lin, Wih + (size_t)l * G_ * D_,
                                               bih + l * G_, bhh + l * G_, gbuf, G_);
        lstm_scan<<<16, 512, 0, stream>>>(gbuf, Whh + (size_t)l * G_ * H_, louts[l]);
        lin = louts[l];
    }

    // post-LSTM instancenorm + projections
    in_stats<<<16, 512, 0, stream>>>(lin, mu_ln, inv_ln);
    apply_in<<<2048, 256, 0, stream>>>(lin, mu_ln, inv_ln, lnorm);
    dim3 g2(64, 2);
    gemm_bias_k128<<<g2, 256, 0, stream>>>(lnorm, proj_h_w, proj_h_b, nullptr, ph, H_);
    gemm_bias_k128<<<g2, 256, 0, stream>>>(xnorm, proj_x_w, proj_x_b, nullptr, px, H_);
    in_stats<<<16, 512, 0, stream>>>(px, mu_px, inv_px);

    // attention + classify
    score_kernel<<<4096, 128, 0, stream>>>(ph, px, mu_px, inv_px, attn_w, lsc);
    softmax_att<<<16, 256, 0, stream>>>(lsc, wsm, out + B_ * NC_);
    final_kernel<<<16, 128, 0, stream>>>(ph, wsm, fc_w, fc_b, out);
}

// Round 2
// 989.237 us; speedup vs baseline: 1.1802x; 1.1802x over previous
//
#include <hip/hip_runtime.h>
#include <math.h>
#include <cstddef>

#define B_ 16
#define T_ 256
#define D_ 128
#define H_ 128
#define L_ 4
#define G_ 512          // 4*H
#define NC_ 10
#define EPS_ 1e-5f

// s_waitcnt immediates: lgkmcnt=15 (no wait), expcnt=7 (no wait), vmcnt low bits
#define WAIT_VM0 0x0F70
#define WAIT_VM1 0x0F71

// ---------------- device helpers ----------------
__device__ __forceinline__ float sigmoid_(float x) {
    x = fminf(fmaxf(x, -30.f), 30.f);
    return 1.f / (1.f + __expf(-x));
}
__device__ __forceinline__ float tanh_(float x) {
    float ax = fminf(fabsf(x), 15.f);
    float e = __expf(2.f * ax);
    float t = 1.f - 2.f / (e + 1.f);
    return copysignf(t, x);
}

#define PIN4(v) asm volatile("" : "+v"(v.x), "+v"(v.y), "+v"(v.z), "+v"(v.w))

// ---------------- stage 1: input normalize ----------------
__global__ __launch_bounds__(512) void stats_bd(const float* __restrict__ x,
                                                float* __restrict__ sum_bd,
                                                float* __restrict__ sq_bd) {
    int b = blockIdx.x;
    int tid = threadIdx.x;
    int d = tid & 127, r = tid >> 7;
    const float* xb = x + (size_t)b * T_ * D_;
    float s = 0.f, q = 0.f;
    for (int t = r; t < T_; t += 4) {
        float v = xb[t * D_ + d];
        s += v; q += v * v;
    }
    __shared__ float ls[512], lq[512];
    ls[tid] = s; lq[tid] = q;
    __syncthreads();
    if (r == 0) {
        s = ls[d] + ls[d + 128] + ls[d + 256] + ls[d + 384];
        q = lq[d] + lq[d + 128] + lq[d + 256] + lq[d + 384];
        sum_bd[b * 128 + d] = s;
        sq_bd[b * 128 + d] = q;
    }
}

__global__ __launch_bounds__(128) void stats_d(const float* __restrict__ sum_bd,
                                               const float* __restrict__ sq_bd,
                                               float* __restrict__ sdv) {
    int d = threadIdx.x;
    float s = 0.f, q = 0.f;
    for (int b = 0; b < B_; b++) { s += sum_bd[b * 128 + d]; q += sq_bd[b * 128 + d]; }
    float n = (float)(B_ * T_);
    float m = s / n;
    float varu = (q - n * m * m) / (n - 1.f);
    varu = fmaxf(varu, 0.f);
    sdv[d] = sqrtf(varu) + EPS_;
}

__global__ __launch_bounds__(256) void normalize_x(const float* __restrict__ x,
                                                   const float* __restrict__ sum_bd,
                                                   const float* __restrict__ sq_bd,
                                                   const float* __restrict__ sdv,
                                                   float* __restrict__ xn) {
    int idx = blockIdx.x * 256 + threadIdx.x;
    int d = idx & 127;
    int b = idx >> 15;
    int bd = b * 128 + d;
    float mu = sum_bd[bd] * (1.f / T_);
    float varT = sq_bd[bd] * (1.f / T_) - mu * mu;
    float s = sdv[d];
    float inv = rsqrtf(fmaxf(varT, 0.f) + EPS_ * s * s);
    xn[idx] = (x[idx] - mu) * inv;
}

// ---------------- generic K=128 GEMM (used for the two projections only) ----------------
__global__ __launch_bounds__(256) void gemm_bias_k128(const float* __restrict__ A,
                                                      const float* __restrict__ Bw,
                                                      const float* __restrict__ b1,
                                                      const float* __restrict__ b2,
                                                      float* __restrict__ C, int N) {
    __shared__ __align__(16) float As[16][64];
    __shared__ __align__(16) float Bs[16][64];
    int tid = threadIdx.x;
    int m0 = blockIdx.x * 64, n0 = blockIdx.y * 64;
    int lr = tid >> 2;
    int lc = (tid & 3) << 2;
    int tm = (tid >> 4) << 2;
    int tn = (tid & 15) << 2;
    float acc[4][4] = {};
    const float* Arow = A + (size_t)(m0 + lr) * 128 + lc;
    const float* Brow = Bw + (size_t)(n0 + lr) * 128 + lc;
    for (int kb = 0; kb < 128; kb += 16) {
        float4 av = *(const float4*)(Arow + kb);
        float4 bv = *(const float4*)(Brow + kb);
        __syncthreads();
        As[lc + 0][lr] = av.x; As[lc + 1][lr] = av.y; As[lc + 2][lr] = av.z; As[lc + 3][lr] = av.w;
        Bs[lc + 0][lr] = bv.x; Bs[lc + 1][lr] = bv.y; Bs[lc + 2][lr] = bv.z; Bs[lc + 3][lr] = bv.w;
        __syncthreads();
#pragma unroll
        for (int k = 0; k < 16; k++) {
            float4 a4 = *(const float4*)&As[k][tm];
            float4 b4 = *(const float4*)&Bs[k][tn];
            float ar[4] = {a4.x, a4.y, a4.z, a4.w};
            float br[4] = {b4.x, b4.y, b4.z, b4.w};
#pragma unroll
            for (int i = 0; i < 4; i++)
#pragma unroll
                for (int j = 0; j < 4; j++)
                    acc[i][j] = fmaf(ar[i], br[j], acc[i][j]);
        }
    }
#pragma unroll
    for (int i = 0; i < 4; i++) {
        int row = m0 + tm + i;
#pragma unroll
        for (int j = 0; j < 4; j++) {
            int col = n0 + tn + j;
            float bias = b1[col] + (b2 ? b2[col] : 0.f);
            C[(size_t)row * N + col] = acc[i][j] + bias;
        }
    }
}

// ---------------- fused pipelined LSTM stack ----------------
// 128 WGs: wg[0..63]   = xproj(l,b)  : gpre[t] = Wih[l] @ in[t] + bih+bhh  -> 16-slot ring
//          wg[64..127] = rec(l,b)    : LSTM recurrence consuming gpre, publishing h
// Cross-WG traffic uses agent-scope atomics (cache-bypass). Flags:
//   flag_h[l*16+b] = k : h_glob[l][b][0..k-1] readable
//   flag_g[l*16+b] = k : gring[l][b][slot of 0..k-1] readable
// Publication is delayed one step; ordering = per-wave s_waitcnt vmcnt(1) + barrier,
// so no wave stalls on its own just-issued stores.
__global__ __attribute__((amdgpu_waves_per_eu(2, 2))) __launch_bounds__(512)
void scan_pipe(const float* __restrict__ xnorm,
               const float* __restrict__ Wih, const float* __restrict__ Whh,
               const float* __restrict__ bih, const float* __restrict__ bhh,
               float* __restrict__ h_glob, float* __restrict__ gring,
               int* __restrict__ flag_h, int* __restrict__ flag_g) {
    const int wg = blockIdx.x;
    const int role = wg >> 6;           // 0 = xproj, 1 = rec
    const int l = (wg >> 4) & 3;
    const int b = wg & 15;
    const int g = threadIdx.x;          // gate row 0..511
    const int lane = g & 63;
    const int wv = g >> 6;

    if (role == 0) {
        // ======== xproj producer ========
        __shared__ __align__(16) float hin[2][128];
        const float4* wr = (const float4*)(Wih + ((size_t)l * G_ + g) * 128);
        float4 w[32];
#pragma unroll
        for (int j = 0; j < 32; j++) w[j] = wr[j];
#pragma unroll
        for (int j = 0; j < 32; j++) PIN4(w[j]);
        float bsum = bih[l * G_ + g] + bhh[l * G_ + g];
        int* fHp = flag_h + (l - 1) * 16 + b;       // producer of our input (l>0 only)
        int* fHo = flag_h + l * 16 + b;             // our consumer's progress (backpressure)
        int* fG = flag_g + l * 16 + b;
        const float* hsrc = (l > 0) ? (h_glob + ((size_t)(l - 1) * 16 + b) * T_ * 128)
                                    : (xnorm + (size_t)b * T_ * 128);
        float* gout = gring + ((size_t)l * 16 + b) * (16 * G_);

        if (wv == 0) {  // stage in[0]
            if (l > 0) {
                int f;
                do { f = __hip_atomic_load(fHp, __ATOMIC_ACQUIRE, __HIP_MEMORY_SCOPE_AGENT); } while (f < 1);
                float v0 = __hip_atomic_load(hsrc + 2 * lane, __ATOMIC_RELAXED, __HIP_MEMORY_SCOPE_AGENT);
                float v1 = __hip_atomic_load(hsrc + 2 * lane + 1, __ATOMIC_RELAXED, __HIP_MEMORY_SCOPE_AGENT);
                hin[0][2 * lane] = v0; hin[0][2 * lane + 1] = v1;
            } else {
                float2 v = *(const float2*)(hsrc + 2 * lane);
                hin[0][2 * lane] = v.x; hin[0][2 * lane + 1] = v.y;
            }
        }
        __syncthreads();

        for (int t = 0; t < T_; t++) {
            __builtin_amdgcn_s_waitcnt(WAIT_VM1);   // all but newest own store complete
            __syncthreads();
            if (g == 0 && t >= 2)
                __hip_atomic_store(fG, t - 1, __ATOMIC_RELAXED, __HIP_MEMORY_SCOPE_AGENT);

            float nv0 = 0.f, nv1 = 0.f;
            bool have = false;
            if (wv == 0 && t + 1 < T_) {
                if (l > 0) {
                    int f;
                    do { f = __hip_atomic_load(fHp, __ATOMIC_ACQUIRE, __HIP_MEMORY_SCOPE_AGENT); } while (f < t + 2);
                }
                {   // ring slot (t+1)&15 must be consumed: rec finished step t-15
                    int f;
                    do { f = __hip_atomic_load(fHo, __ATOMIC_ACQUIRE, __HIP_MEMORY_SCOPE_AGENT); } while (f < t - 14);
                }
                if (l > 0) {
                    nv0 = __hip_atomic_load(hsrc + (size_t)(t + 1) * 128 + 2 * lane, __ATOMIC_RELAXED, __HIP_MEMORY_SCOPE_AGENT);
                    nv1 = __hip_atomic_load(hsrc + (size_t)(t + 1) * 128 + 2 * lane + 1, __ATOMIC_RELAXED, __HIP_MEMORY_SCOPE_AGENT);
                } else {
                    float2 v = *(const float2*)(hsrc + (size_t)(t + 1) * 128 + 2 * lane);
                    nv0 = v.x; nv1 = v.y;
                }
                have = true;
            }

            const float4* hb = (const float4*)hin[t & 1];
            float d0 = 0.f, d1 = 0.f, d2 = 0.f, d3 = 0.f;
#pragma unroll
            for (int j = 0; j < 32; j++) {
                float4 hv = hb[j];
                d0 = fmaf(w[j].x, hv.x, d0);
                d1 = fmaf(w[j].y, hv.y, d1);
                d2 = fmaf(w[j].z, hv.z, d2);
                d3 = fmaf(w[j].w, hv.w, d3);
            }
            float z = bsum + ((d0 + d1) + (d2 + d3));
            __hip_atomic_store(gout + (size_t)(t & 15) * G_ + g, z, __ATOMIC_RELAXED, __HIP_MEMORY_SCOPE_AGENT);
            if (have) { hin[(t + 1) & 1][2 * lane] = nv0; hin[(t + 1) & 1][2 * lane + 1] = nv1; }
            __syncthreads();
        }
        __builtin_amdgcn_s_waitcnt(WAIT_VM0);
        __syncthreads();
        if (g == 0) __hip_atomic_store(fG, T_, __ATOMIC_RELAXED, __HIP_MEMORY_SCOPE_AGENT);
    } else {
        // ======== rec consumer ========
        __shared__ __align__(16) float hsh[128];
        __shared__ float gact[512];
        const float4* wr = (const float4*)(Whh + ((size_t)l * G_ + g) * 128);
        float4 w[32];
#pragma unroll
        for (int j = 0; j < 32; j++) w[j] = wr[j];
#pragma unroll
        for (int j = 0; j < 32; j++) PIN4(w[j]);
        int* fG = flag_g + l * 16 + b;
        int* fH = flag_h + l * 16 + b;
        const float* gsrc = gring + ((size_t)l * 16 + b) * (16 * G_) + g;
        float* hob = h_glob + ((size_t)l * 16 + b) * T_ * 128;
        float c = 0.f;
        if (g < 128) hsh[g] = 0.f;
        int Fg;
        do { Fg = __hip_atomic_load(fG, __ATOMIC_ACQUIRE, __HIP_MEMORY_SCOPE_AGENT); } while (Fg < 1);
        float pre = __hip_atomic_load(gsrc, __ATOMIC_RELAXED, __HIP_MEMORY_SCOPE_AGENT);  // slot 0
        __syncthreads();

        for (int t = 0; t < T_; t++) {
            __builtin_amdgcn_s_waitcnt(WAIT_VM1);
            __syncthreads();
            if (g == 0 && t >= 2)
                __hip_atomic_store(fH, t - 1, __ATOMIC_RELAXED, __HIP_MEMORY_SCOPE_AGENT);

            float pre_nxt = 0.f;
            int FgNew = Fg;
            if (t + 1 < T_) {
                FgNew = __hip_atomic_load(fG, __ATOMIC_RELAXED, __HIP_MEMORY_SCOPE_AGENT);  // prefetch for next step
                if (Fg < t + 2) {
                    do { Fg = __hip_atomic_load(fG, __ATOMIC_ACQUIRE, __HIP_MEMORY_SCOPE_AGENT); } while (Fg < t + 2);
                }
                pre_nxt = __hip_atomic_load(gsrc + (size_t)((t + 1) & 15) * G_, __ATOMIC_RELAXED, __HIP_MEMORY_SCOPE_AGENT);
            }

            float d0 = 0.f, d1 = 0.f, d2 = 0.f, d3 = 0.f;
            const float4* h4 = (const float4*)hsh;
#pragma unroll
            for (int j = 0; j < 32; j++) {
                float4 hv = h4[j];
                d0 = fmaf(w[j].x, hv.x, d0);
                d1 = fmaf(w[j].y, hv.y, d1);
                d2 = fmaf(w[j].z, hv.z, d2);
                d3 = fmaf(w[j].w, hv.w, d3);
            }
            float z = pre + ((d0 + d1) + (d2 + d3));
            float a = ((g >> 7) == 2) ? tanh_(z) : sigmoid_(z);
            gact[g] = a;
            __syncthreads();
            if (g < 128) {
                float ai = gact[g], af = gact[128 + g], ag = gact[256 + g], ao = gact[384 + g];
                c = fmaf(af, c, ai * ag);
                float hn = ao * tanh_(c);
                hsh[g] = hn;
                __hip_atomic_store(hob + (size_t)t * 128 + g, hn, __ATOMIC_RELAXED, __HIP_MEMORY_SCOPE_AGENT);
            }
            pre = pre_nxt;
            Fg = (FgNew > Fg) ? FgNew : Fg;
        }
        __builtin_amdgcn_s_waitcnt(WAIT_VM0);
        __syncthreads();
        if (g == 0) __hip_atomic_store(fH, T_, __ATOMIC_RELAXED, __HIP_MEMORY_SCOPE_AGENT);
    }
}

// ---------------- InstanceNorm stats ----------------
__global__ __launch_bounds__(512) void in_stats(const float* __restrict__ in,
                                                float* __restrict__ mu,
                                                float* __restrict__ inv) {
    int b = blockIdx.x;
    int tid = threadIdx.x;
    int h = tid & 127, r = tid >> 7;
    const float* ib = in + (size_t)b * T_ * H_;
    float s = 0.f, q = 0.f;
    for (int t = r; t < T_; t += 4) { float v = ib[t * H_ + h]; s += v; q += v * v; }
    __shared__ float ls[512], lq[512];
    ls[tid] = s; lq[tid] = q;
    __syncthreads();
    if (r == 0) {
        s = ls[h] + ls[h + 128] + ls[h + 256] + ls[h + 384];
        q = lq[h] + lq[h + 128] + lq[h + 256] + lq[h + 384];
        float m = s * (1.f / T_);
        float v = q * (1.f / T_) - m * m;
        mu[b * 128 + h] = m;
        inv[b * 128 + h] = rsqrtf(fmaxf(v, 0.f) + EPS_);
    }
}

__global__ __launch_bounds__(256) void apply_in(const float* __restrict__ in,
                                                const float* __restrict__ mu,
                                                const float* __restrict__ inv,
                                                float* __restrict__ out) {
    int idx = blockIdx.x * 256 + threadIdx.x;
    int h = idx & 127;
    int b = idx >> 15;
    out[idx] = (in[idx] - mu[b * 128 + h]) * inv[b * 128 + h];
}

// ---------------- attention score ----------------
__global__ __launch_bounds__(128) void score_kernel(const float* __restrict__ ph,
                                                    const float* __restrict__ px,
                                                    const float* __restrict__ mu_px,
                                                    const float* __restrict__ inv_px,
                                                    const float* __restrict__ attn_w,
                                                    float* __restrict__ lsc) {
    int bt = blockIdx.x;
    int b = bt >> 8;
    int h = threadIdx.x;
    size_t o = (size_t)bt * 128 + h;
    float v = ph[o] + (px[o] - mu_px[b * 128 + h]) * inv_px[b * 128 + h];
    float sv = tanh_(v) * attn_w[h];
    __shared__ float red[128];
    red[h] = sv;
    __syncthreads();
    for (int off = 64; off > 0; off >>= 1) {
        if (h < off) red[h] += red[h + off];
        __syncthreads();
    }
    if (h == 0) lsc[bt] = red[0];
}

__global__ __launch_bounds__(256) void softmax_att(const float* __restrict__ lsc,
                                                   float* __restrict__ wsm,
                                                   float* __restrict__ out_att) {
    int b = blockIdx.x;
    int t = threadIdx.x;
    float v = lsc[b * 256 + t];
    __shared__ float red[256];
    red[t] = v; __syncthreads();
    for (int off = 128; off > 0; off >>= 1) { if (t < off) red[t] = fmaxf(red[t], red[t + off]); __syncthreads(); }
    float mx = red[0]; __syncthreads();
    float e = __expf(v - mx);
    red[t] = e; __syncthreads();
    for (int off = 128; off > 0; off >>= 1) { if (t < off) red[t] += red[t + off]; __syncthreads(); }
    float s = red[0];
    float w = e / s;
    wsm[b * 256 + t] = w;
    __shared__ float wl[256];
    wl[t] = w; __syncthreads();
    float* ob = out_att + (size_t)b * T_ * D_;
    const float invD = 1.f / (float)D_;
    for (int i = t; i < T_ * D_; i += 256) ob[i] = wl[i >> 7] * invD;
}

__global__ __launch_bounds__(128) void final_kernel(const float* __restrict__ ph,
                                                    const float* __restrict__ wsm,
                                                    const float* __restrict__ fc_w,
                                                    const float* __restrict__ fc_b,
                                                    float* __restrict__ out) {
    int b = blockIdx.x;
    int h = threadIdx.x;
    const float* pb = ph + (size_t)b * T_ * H_;
    const float* wb = wsm + b * 256;
    float acc = 0.f;
    for (int t = 0; t < T_; t++) acc = fmaf(pb[t * H_ + h], wb[t], acc);
    __shared__ float ctx[128];
    ctx[h] = acc;
    __syncthreads();
    if (h < NC_) {
        float s = fc_b[h];
        const float* fw = fc_w + h * 128;
        for (int k = 0; k < 128; k++) s = fmaf(ctx[k], fw[k], s);
        out[b * NC_ + h] = s;
    }
}

// ---------------- launcher ----------------
extern "C" void kernel_launch(void* const* d_in, const int* in_sizes, int n_in,
                              void* d_out, int out_size, void* d_ws, size_t ws_size,
                              hipStream_t stream) {
    const float* x        = (const float*)d_in[0];
    const float* Wih      = (const float*)d_in[1];
    const float* Whh      = (const float*)d_in[2];
    const float* bih      = (const float*)d_in[3];
    const float* bhh      = (const float*)d_in[4];
    const float* proj_h_w = (const float*)d_in[5];
    const float* proj_h_b = (const float*)d_in[6];
    const float* proj_x_w = (const float*)d_in[7];
    const float* proj_x_b = (const float*)d_in[8];
    const float* attn_w   = (const float*)d_in[9];
    const float* fc_w     = (const float*)d_in[10];
    const float* fc_b     = (const float*)d_in[11];
    float* out = (float*)d_out;

    float* ws = (float*)d_ws;
    const size_t NTD = (size_t)B_ * T_ * D_;       // 524288
    float* xnorm  = ws;                            // [0, NTD)
    float* h_glob = xnorm + NTD;                   // [NTD, 5*NTD)   4 layers of h
    float* gring  = h_glob + 4 * NTD;              // [5*NTD, 6*NTD) 4*16*16*512
    float* smalls = gring + NTD;
    float* sum_bd = smalls;
    float* sq_bd  = sum_bd + 2048;
    float* sdv    = sq_bd + 2048;
    float* mu_ln  = sdv + 128;
    float* inv_ln = mu_ln + 2048;
    float* mu_px  = inv_ln + 2048;
    float* inv_px = mu_px + 2048;
    float* lsc    = inv_px + 2048;
    float* wsm    = lsc + 4096;
    int*   flags  = (int*)(wsm + 4096);            // flag_h[64] + flag_g[64]
    int*   flag_h = flags;
    int*   flag_g = flags + 64;
    // buffers reused after the scan completes (dispatch-boundary ordering):
    float* lnorm = gring;                          // gring dead after scan
    float* ph    = h_glob;                         // h layers 0/1 dead after scan
    float* px    = h_glob + NTD;
    const float* h3 = h_glob + 3 * NTD;            // layer-3 h, [B][T][H]

    hipMemsetAsync((void*)flags, 0, 128 * sizeof(int), stream);

    // input normalize
    stats_bd<<<16, 512, 0, stream>>>(x, sum_bd, sq_bd);
    stats_d<<<1, 128, 0, stream>>>(sum_bd, sq_bd, sdv);
    normalize_x<<<2048, 256, 0, stream>>>(x, sum_bd, sq_bd, sdv, xnorm);

    // fused pipelined 4-layer LSTM (replaces 4 GEMMs + 4 scans)
    scan_pipe<<<128, 512, 0, stream>>>(xnorm, Wih, Whh, bih, bhh,
                                       h_glob, gring, flag_h, flag_g);

    // post-LSTM instancenorm + projections
    in_stats<<<16, 512, 0, stream>>>(h3, mu_ln, inv_ln);
    apply_in<<<2048, 256, 0, stream>>>(h3, mu_ln, inv_ln, lnorm);
    dim3 g2(64, 2);
    gemm_bias_k128<<<g2, 256, 0, stream>>>(lnorm, proj_h_w, proj_h_b, nullptr, ph, H_);
    gemm_bias_k128<<<g2, 256, 0, stream>>>(xnorm, proj_x_w, proj_x_b, nullptr, px, H_);
    in_stats<<<16, 512, 0, stream>>>(px, mu_px, inv_px);

    // attention + classify
    score_kernel<<<4096, 128, 0, stream>>>(ph, px, mu_px, inv_px, attn_w, lsc);
    softmax_att<<<16, 256, 0, stream>>>(lsc, wsm, out + B_ * NC_);
    final_kernel<<<16, 128, 0, stream>>>(ph, wsm, fc_w, fc_b, out);
}